// Round 1
// baseline (382.342 us; speedup 1.0000x reference)
//
#include <hip/hip_runtime.h>
#include <hip/hip_bf16.h>

#define Dm 128
#define Vn 8
#define VHn 40
#define BTOT (32 * 2048)

// Precomputed combined operators (written by k_combine/k_mt each call; read by fused kernel).
__device__ float g_Wq[Dm * Dm];   // Wq_c[g][d] = sum_f wq[g][f] * p_w2[f][d]
__device__ float g_Wk[Dm * Dm];
__device__ float g_bq[Dm], g_bk[Dm];
__device__ float g_MT[Dm * Dm];   // MT[e*128+d] = M[d][e] = sum_g Wq_c[g][d]*Wk_c[g][e]
__device__ float g_u[Dm];         // u[d] = sum_g Wq_c[g][d]*bk[g]
__device__ float g_w[Dm];         // w[e] = sum_g Wk_c[g][e]*bq[g]
__device__ float g_c[1];          // c = bq . bk

__device__ __forceinline__ float fast_sigmoid(float x) { return 1.0f / (1.0f + __expf(-x)); }
__device__ __forceinline__ float fast_tanh(float x) { return 1.0f - 2.0f / (__expf(2.0f * x) + 1.0f); }

__global__ __launch_bounds__(128) void k_combine(const float* __restrict__ wq,
                                                 const float* __restrict__ wk,
                                                 const float* __restrict__ pw2,
                                                 const float* __restrict__ pb2) {
    int g = blockIdx.x, d = threadIdx.x;
    float aq = 0.f, ak = 0.f;
    for (int f = 0; f < Dm; ++f) {
        float pv = pw2[f * Dm + d];
        aq = fmaf(wq[g * Dm + f], pv, aq);
        ak = fmaf(wk[g * Dm + f], pv, ak);
    }
    g_Wq[g * Dm + d] = aq;
    g_Wk[g * Dm + d] = ak;
    if (d == 0) {
        float bq = 0.f, bk = 0.f;
        for (int f = 0; f < Dm; ++f) {
            bq = fmaf(wq[g * Dm + f], pb2[f], bq);
            bk = fmaf(wk[g * Dm + f], pb2[f], bk);
        }
        g_bq[g] = bq;
        g_bk[g] = bk;
    }
}

__global__ __launch_bounds__(128) void k_mt() {
    int e = blockIdx.x, d = threadIdx.x;
    float acc = 0.f, uacc = 0.f, wacc = 0.f;
    for (int g = 0; g < Dm; ++g) {
        float a = g_Wq[g * Dm + d], b = g_Wk[g * Dm + e];
        acc = fmaf(a, b, acc);
        uacc = fmaf(a, g_bk[g], uacc);
        wacc = fmaf(b, g_bq[g], wacc);
    }
    g_MT[e * Dm + d] = acc;
    if (e == 0) g_u[d] = uacc;
    if (d == 0) g_w[e] = wacc;
    if (e == 0 && d == 0) {
        float c = 0.f;
        for (int g = 0; g < Dm; ++g) c = fmaf(g_bq[g], g_bk[g], c);
        g_c[0] = c;
    }
}

// 128 threads = 2 waves; each wave handles 2 positions (bt).
__global__ __launch_bounds__(128) void k_fused(const float* __restrict__ x,
                                               const float* __restrict__ hist,
                                               const float* __restrict__ ce_w1,
                                               const float* __restrict__ ce_b1,
                                               const float* __restrict__ ce_w2,
                                               const float* __restrict__ ce_b2,
                                               const float* __restrict__ p_w1,
                                               const float* __restrict__ p_b1,
                                               float* __restrict__ pred_out,
                                               float* __restrict__ A_out) {
    __shared__ __align__(16) float rp_s[2][2][8][132];  // [wave][pos][i][d] pad 132
    __shared__ __align__(16) float z_s[2][2][8][132];   // Z'_j[d] = (M rp_j)[d] + u[d]
    __shared__ __align__(16) float h_s[2][2][128];
    __shared__ float sj_s[2][2][8];                     // w.rp_j + c

    const int wv = threadIdx.x >> 6;
    const int l = threadIdx.x & 63;
    const int d0 = 2 * l, d1 = 2 * l + 1;
    const long bt0 = (long)blockIdx.x * 4 + wv * 2;

    // ---- rp: relu(x_i * p_w1 + p_b1) ----
    float2 w1v = *(const float2*)&p_w1[d0];
    float2 b1v = *(const float2*)&p_b1[d0];
#pragma unroll
    for (int p = 0; p < 2; ++p) {
        const float* xp = x + (bt0 + p) * 8;
#pragma unroll
        for (int i = 0; i < 8; ++i) {
            float xv = xp[i];
            rp_s[wv][p][i][d0] = fmaxf(fmaf(xv, w1v.x, b1v.x), 0.f);
            rp_s[wv][p][i][d1] = fmaxf(fmaf(xv, w1v.y, b1v.y), 0.f);
        }
    }

    // ---- h = relu(hist @ ce_w1.T + ce_b1), both positions ----
    {
        float c1a = ce_b1[d0], c1b = ce_b1[d1];
        float h00 = c1a, h01 = c1b, h10 = c1a, h11 = c1b;
        const float* w1r0 = ce_w1 + (size_t)d0 * VHn;
        const float* w1r1 = ce_w1 + (size_t)d1 * VHn;
        const float* hh0 = hist + bt0 * VHn;
        const float* hh1 = hh0 + VHn;
#pragma unroll 8
        for (int m = 0; m < VHn; ++m) {
            float wa = w1r0[m], wb = w1r1[m];
            float v0 = hh0[m], v1 = hh1[m];
            h00 = fmaf(wa, v0, h00);
            h01 = fmaf(wb, v0, h01);
            h10 = fmaf(wa, v1, h10);
            h11 = fmaf(wb, v1, h11);
        }
        h_s[wv][0][d0] = fmaxf(h00, 0.f);
        h_s[wv][0][d1] = fmaxf(h01, 0.f);
        h_s[wv][1][d0] = fmaxf(h10, 0.f);
        h_s[wv][1][d1] = fmaxf(h11, 0.f);
    }

    // ---- s_j = w . rp_j + c (16 lanes) ----
    if (l < 16) {
        int p = l >> 3, j = l & 7;
        float acc = g_c[0];
#pragma unroll 8
        for (int e = 0; e < Dm; ++e) acc = fmaf(g_w[e], rp_s[wv][p][j][e], acc);
        sj_s[wv][p][j] = acc;
    }

    // ---- gate logits: lane owns o = i*8+j = l ----
    float g0 = ce_b2[l], g1 = g0;
    {
        const float* w2r = ce_w2 + (size_t)l * Dm;
#pragma unroll 4
        for (int d4 = 0; d4 < 32; ++d4) {
            float4 w2 = *(const float4*)&w2r[4 * d4];
            float4 ha = *(const float4*)&h_s[wv][0][4 * d4];
            float4 hb = *(const float4*)&h_s[wv][1][4 * d4];
            g0 = fmaf(w2.x, ha.x, g0); g0 = fmaf(w2.y, ha.y, g0);
            g0 = fmaf(w2.z, ha.z, g0); g0 = fmaf(w2.w, ha.w, g0);
            g1 = fmaf(w2.x, hb.x, g1); g1 = fmaf(w2.y, hb.y, g1);
            g1 = fmaf(w2.z, hb.z, g1); g1 = fmaf(w2.w, hb.w, g1);
        }
    }
    const float gate0 = fast_sigmoid(g0);
    const float gate1 = fast_sigmoid(g1);

    // ---- Z = M @ rp + u : lane owns d0,d1; loop e; M read from L1/L2 ----
    float zac[2][8][2];
#pragma unroll
    for (int p = 0; p < 2; ++p)
#pragma unroll
        for (int i = 0; i < 8; ++i) { zac[p][i][0] = 0.f; zac[p][i][1] = 0.f; }

#pragma unroll 2
    for (int e4 = 0; e4 < 32; ++e4) {
        float4 rv[2][8];
#pragma unroll
        for (int p = 0; p < 2; ++p)
#pragma unroll
            for (int i = 0; i < 8; ++i) rv[p][i] = *(const float4*)&rp_s[wv][p][i][4 * e4];
        float2 mt0 = *(const float2*)&g_MT[(4 * e4 + 0) * Dm + d0];
        float2 mt1 = *(const float2*)&g_MT[(4 * e4 + 1) * Dm + d0];
        float2 mt2 = *(const float2*)&g_MT[(4 * e4 + 2) * Dm + d0];
        float2 mt3 = *(const float2*)&g_MT[(4 * e4 + 3) * Dm + d0];
#pragma unroll
        for (int p = 0; p < 2; ++p)
#pragma unroll
            for (int i = 0; i < 8; ++i) {
                float4 r = rv[p][i];
                zac[p][i][0] = fmaf(mt0.x, r.x, zac[p][i][0]);
                zac[p][i][0] = fmaf(mt1.x, r.y, zac[p][i][0]);
                zac[p][i][0] = fmaf(mt2.x, r.z, zac[p][i][0]);
                zac[p][i][0] = fmaf(mt3.x, r.w, zac[p][i][0]);
                zac[p][i][1] = fmaf(mt0.y, r.x, zac[p][i][1]);
                zac[p][i][1] = fmaf(mt1.y, r.y, zac[p][i][1]);
                zac[p][i][1] = fmaf(mt2.y, r.z, zac[p][i][1]);
                zac[p][i][1] = fmaf(mt3.y, r.w, zac[p][i][1]);
            }
    }
    {
        float2 uv = *(const float2*)&g_u[d0];
#pragma unroll
        for (int p = 0; p < 2; ++p)
#pragma unroll
            for (int i = 0; i < 8; ++i) {
                z_s[wv][p][i][d0] = zac[p][i][0] + uv.x;
                z_s[wv][p][i][d1] = zac[p][i][1] + uv.y;
            }
    }

    // ---- scores / A / pred: lane = (i,j) ----
    const int si = l >> 3, sjj = l & 7;
#pragma unroll 1
    for (int p = 0; p < 2; ++p) {
        float acc = sj_s[wv][p][sjj];
#pragma unroll 8
        for (int d4 = 0; d4 < 32; ++d4) {
            float4 a = *(const float4*)&rp_s[wv][p][si][4 * d4];
            float4 zb = *(const float4*)&z_s[wv][p][sjj][4 * d4];
            acc = fmaf(a.x, zb.x, acc);
            acc = fmaf(a.y, zb.y, acc);
            acc = fmaf(a.z, zb.z, acc);
            acc = fmaf(a.w, zb.w, acc);
        }
        float sc = acc * 0.08838834764831845f;  // 1/sqrt(128)
        float gate = (p == 0) ? gate0 : gate1;
        float Aval = fast_tanh(sc) * gate;
        A_out[(bt0 + p) * 64 + l] = Aval;
        float pr = Aval * x[(bt0 + p) * 8 + sjj];
        pr += __shfl_xor(pr, 1);
        pr += __shfl_xor(pr, 2);
        pr += __shfl_xor(pr, 4);
        if (sjj == 0) pred_out[(bt0 + p) * 8 + si] = pr;
    }
}

extern "C" void kernel_launch(void* const* d_in, const int* in_sizes, int n_in,
                              void* d_out, int out_size, void* d_ws, size_t ws_size,
                              hipStream_t stream) {
    const float* x = (const float*)d_in[0];
    const float* hist = (const float*)d_in[1];
    const float* ce_w1 = (const float*)d_in[2];
    const float* ce_b1 = (const float*)d_in[3];
    const float* ce_w2 = (const float*)d_in[4];
    const float* ce_b2 = (const float*)d_in[5];
    const float* p_w1 = (const float*)d_in[6];
    const float* p_b1 = (const float*)d_in[7];
    const float* p_w2 = (const float*)d_in[8];
    const float* p_b2 = (const float*)d_in[9];
    const float* wq = (const float*)d_in[10];
    const float* wk = (const float*)d_in[11];

    float* pred_out = (float*)d_out;
    float* A_out = pred_out + (size_t)BTOT * Vn;

    k_combine<<<Dm, Dm, 0, stream>>>(wq, wk, p_w2, p_b2);
    k_mt<<<Dm, Dm, 0, stream>>>();
    k_fused<<<BTOT / 4, 128, 0, stream>>>(x, hist, ce_w1, ce_b1, ce_w2, ce_b2,
                                          p_w1, p_b1, pred_out, A_out);
}

// Round 2
// 324.079 us; speedup vs baseline: 1.1798x; 1.1798x over previous
//
#include <hip/hip_runtime.h>
#include <hip/hip_bf16.h>
#include <stdint.h>

#define Dm 128
#define BTOT (32 * 2048)

typedef short s16x8 __attribute__((ext_vector_type(8)));
typedef float f32x4 __attribute__((ext_vector_type(4)));

__device__ float g_Wq[Dm * Dm];   // Wq_c[g][d] = sum_f wq[g][f] * p_w2[f][d]
__device__ float g_Wk[Dm * Dm];
__device__ float g_bq[Dm], g_bk[Dm];
__device__ __align__(16) unsigned short g_Mfrag[32 * 64 * 8]; // bf16 A-frags of M
__device__ float g_u[Dm], g_w[Dm], g_c[1];

__device__ __forceinline__ float fast_sigmoid(float x) { return 1.0f / (1.0f + __expf(-x)); }
__device__ __forceinline__ float fast_tanh(float x) { return 1.0f - 2.0f / (__expf(2.0f * x) + 1.0f); }

__device__ __forceinline__ unsigned short f2bf(float f) {  // RNE f32->bf16
    unsigned u = __float_as_uint(f);
    u += 0x7fffu + ((u >> 16) & 1u);
    return (unsigned short)(u >> 16);
}

__global__ __launch_bounds__(128) void k_combine(const float* __restrict__ wq,
                                                 const float* __restrict__ wk,
                                                 const float* __restrict__ pw2,
                                                 const float* __restrict__ pb2) {
    int g = blockIdx.x, d = threadIdx.x;
    float aq = 0.f, ak = 0.f;
    for (int f = 0; f < Dm; ++f) {
        float pv = pw2[f * Dm + d];
        aq = fmaf(wq[g * Dm + f], pv, aq);
        ak = fmaf(wk[g * Dm + f], pv, ak);
    }
    g_Wq[g * Dm + d] = aq;
    g_Wk[g * Dm + d] = ak;
    if (d == 0) {
        float bq = 0.f, bk = 0.f;
        for (int f = 0; f < Dm; ++f) {
            bq = fmaf(wq[g * Dm + f], pb2[f], bq);
            bk = fmaf(wk[g * Dm + f], pb2[f], bk);
        }
        g_bq[g] = bq;
        g_bk[g] = bk;
    }
}

__global__ __launch_bounds__(128) void k_uwc() {
    int d = threadIdx.x;
    float ua = 0.f, wa = 0.f;
    for (int g = 0; g < Dm; ++g) {
        ua = fmaf(g_Wq[g * Dm + d], g_bk[g], ua);
        wa = fmaf(g_Wk[g * Dm + d], g_bq[g], wa);
    }
    g_u[d] = ua;
    g_w[d] = wa;
    if (d == 0) {
        float c = 0.f;
        for (int g = 0; g < Dm; ++g) c = fmaf(g_bq[g], g_bk[g], c);
        g_c[0] = c;
    }
}

// Pack M[row][e] = sum_g Wq_c[g][row] * Wk_c[g][e] into bf16 A-fragments.
// k-map f(g,j) = 4g + (j&3) + 16*(j>>2) — consistent across all frag producers.
__global__ __launch_bounds__(64) void k_frag() {
    int t = blockIdx.x;          // t = rtile*4 + kchunk, 0..31
    int kc = t & 3;
    int rt = t >> 2;
    int l = threadIdx.x;
    int row = rt * 16 + (l & 15);
    int g = l >> 4;
#pragma unroll
    for (int j = 0; j < 8; ++j) {
        int e = kc * 32 + 4 * g + (j & 3) + 16 * (j >> 2);
        float acc = 0.f;
        for (int gg = 0; gg < Dm; ++gg)
            acc = fmaf(g_Wq[gg * Dm + row], g_Wk[gg * Dm + e], acc);
        g_Mfrag[(t * 64 + l) * 8 + j] = f2bf(acc);
    }
}

// 256 threads = 4 waves; each wave handles 2 positions (16 RP columns).
__global__ __launch_bounds__(256, 4) void k_fused(const float* __restrict__ x,
                                                  const float* __restrict__ hist,
                                                  const float* __restrict__ ce_w1,
                                                  const float* __restrict__ ce_b1,
                                                  const float* __restrict__ ce_w2,
                                                  const float* __restrict__ ce_b2,
                                                  const float* __restrict__ p_w1,
                                                  const float* __restrict__ p_b1,
                                                  float* __restrict__ pred_out,
                                                  float* __restrict__ A_out) {
    __shared__ __align__(16) unsigned short m_lds[32 * 64 * 8];  // 32 KB
    __shared__ __align__(16) float h_s[4][2][128];               // 4 KB
    __shared__ float gate_s[4][2][64];                           // 2 KB

    const int tid = threadIdx.x;
    const int wv = tid >> 6;
    const int l = tid & 63;
    const int g = l >> 4, c16 = l & 15;
    const long bt0 = (long)blockIdx.x * 8 + wv * 2;

    // ---- stage M fragments: global -> LDS, async, drained by the barrier ----
    {
        const char* gsrc = (const char*)g_Mfrag + (size_t)wv * 8192 + (size_t)l * 16;
        char* lbase = (char*)m_lds + wv * 8192;
#pragma unroll
        for (int q = 0; q < 8; ++q) {
            __builtin_amdgcn_global_load_lds(
                (const __attribute__((address_space(1))) unsigned int*)(gsrc + q * 1024),
                (__attribute__((address_space(3))) unsigned int*)(lbase + q * 1024),
                16, 0, 0);
        }
    }

    // ---- rp fragments (bf16, frag layout) + su/sj affine partials ----
    const int p_me = c16 >> 3, i_me = c16 & 7;
    const float xv = x[(bt0 + p_me) * 8 + i_me];
    s16x8 rpf[4];
    float su = 0.f, sj = 0.f;
#pragma unroll
    for (int kc = 0; kc < 4; ++kc) {
#pragma unroll
        for (int jh = 0; jh < 2; ++jh) {
            int d4 = kc * 32 + 4 * g + 16 * jh;
            f32x4 w1v = *(const f32x4*)&p_w1[d4];
            f32x4 b1v = *(const f32x4*)&p_b1[d4];
            f32x4 uv = *(const f32x4*)&g_u[d4];
            f32x4 wvv = *(const f32x4*)&g_w[d4];
#pragma unroll
            for (int jj = 0; jj < 4; ++jj) {
                float val = fmaxf(fmaf(xv, w1v[jj], b1v[jj]), 0.f);
                su = fmaf(uv[jj], val, su);
                sj = fmaf(wvv[jj], val, sj);
                rpf[kc][jh * 4 + jj] = (short)f2bf(val);
            }
        }
    }
    su += __shfl_xor(su, 16); su += __shfl_xor(su, 32);  // full u.rp_{c16}
    sj += __shfl_xor(sj, 16); sj += __shfl_xor(sj, 32);  // full w.rp_{c16}

    // ---- h = relu(hist @ ce_w1.T + ce_b1), both positions ----
    {
        const int d0 = 2 * l, d1 = 2 * l + 1;
        float c1a = ce_b1[d0], c1b = ce_b1[d1];
        float h00 = c1a, h01 = c1b, h10 = c1a, h11 = c1b;
        const float* w1r0 = ce_w1 + (size_t)d0 * 40;
        const float* w1r1 = ce_w1 + (size_t)d1 * 40;
        const float* hh0 = hist + bt0 * 40;
        const float* hh1 = hh0 + 40;
#pragma unroll 8
        for (int m = 0; m < 40; ++m) {
            float wa = w1r0[m], wb = w1r1[m];
            float v0 = hh0[m], v1 = hh1[m];
            h00 = fmaf(wa, v0, h00);
            h01 = fmaf(wb, v0, h01);
            h10 = fmaf(wa, v1, h10);
            h11 = fmaf(wb, v1, h11);
        }
        h_s[wv][0][d0] = fmaxf(h00, 0.f);
        h_s[wv][0][d1] = fmaxf(h01, 0.f);
        h_s[wv][1][d0] = fmaxf(h10, 0.f);
        h_s[wv][1][d1] = fmaxf(h11, 0.f);
    }

    // ---- gate (lane = output index o = i*8+j), both positions ----
    {
        float g0 = ce_b2[l], g1 = g0;
        const float* w2r = ce_w2 + (size_t)l * Dm;
#pragma unroll 4
        for (int d4 = 0; d4 < 32; ++d4) {
            f32x4 w2 = *(const f32x4*)&w2r[4 * d4];
            f32x4 ha = *(const f32x4*)&h_s[wv][0][4 * d4];
            f32x4 hb = *(const f32x4*)&h_s[wv][1][4 * d4];
#pragma unroll
            for (int jj = 0; jj < 4; ++jj) {
                g0 = fmaf(w2[jj], ha[jj], g0);
                g1 = fmaf(w2[jj], hb[jj], g1);
            }
        }
        gate_s[wv][0][l] = fast_sigmoid(g0);
        gate_s[wv][1][l] = fast_sigmoid(g1);
    }

    __syncthreads();  // m_lds staged (vmcnt drained) + visible to all waves

    // ---- Y = M @ RP : 32 MFMAs ----
    f32x4 Yacc[8];
#pragma unroll
    for (int r = 0; r < 8; ++r) Yacc[r] = (f32x4){0.f, 0.f, 0.f, 0.f};
#pragma unroll
    for (int kc = 0; kc < 4; ++kc) {
#pragma unroll
        for (int r = 0; r < 8; ++r) {
            s16x8 af = *(const s16x8*)&m_lds[((r * 4 + kc) * 64 + l) * 8];
            Yacc[r] = __builtin_amdgcn_mfma_f32_16x16x32_bf16(af, rpf[kc], Yacc[r], 0, 0, 0);
        }
    }

    // ---- Y (C-layout) -> bf16 B-frags: direct feed under chosen k-map ----
    s16x8 yf[4];
#pragma unroll
    for (int kc = 0; kc < 4; ++kc) {
#pragma unroll
        for (int jj = 0; jj < 4; ++jj) {
            yf[kc][jj] = (short)f2bf(Yacc[2 * kc][jj]);
            yf[kc][4 + jj] = (short)f2bf(Yacc[2 * kc + 1][jj]);
        }
    }

    // ---- S = RP^T @ Y : 4 MFMAs ----
    f32x4 Sacc = (f32x4){0.f, 0.f, 0.f, 0.f};
#pragma unroll
    for (int kc = 0; kc < 4; ++kc)
        Sacc = __builtin_amdgcn_mfma_f32_16x16x32_bf16(rpf[kc], yf[kc], Sacc, 0, 0, 0);

    // ---- epilogue: scores -> A, pred ----
    const float cc = g_c[0];
    const int np = c16 >> 3, jv = c16 & 7;        // column identity (position, j)
    const bool diag = ((g >> 1) == np);           // row-position == col-position
    float Av[4], pr[4];
#pragma unroll
    for (int q = 0; q < 4; ++q) {
        float su_i = __shfl(su, 4 * g + q);       // u.rp for row i_full = 4g+q
        float sc = (Sacc[q] + su_i + sj + cc) * 0.08838834764831845f;
        float gv = gate_s[wv][np][((g & 1) * 4 + q) * 8 + jv];
        Av[q] = fast_tanh(sc) * gv;
        pr[q] = Av[q] * xv;                       // xv = x[(bt0+np)*8 + jv]
        pr[q] += __shfl_xor(pr[q], 1);
        pr[q] += __shfl_xor(pr[q], 2);
        pr[q] += __shfl_xor(pr[q], 4);
    }
    if (diag) {
        float* Ap = A_out + (bt0 + np) * 64 + jv;
#pragma unroll
        for (int q = 0; q < 4; ++q) Ap[((g & 1) * 4 + q) * 8] = Av[q];
        if (jv == 0) {
            float* Pp = pred_out + (bt0 + np) * 8 + (g & 1) * 4;
#pragma unroll
            for (int q = 0; q < 4; ++q) Pp[q] = pr[q];
        }
    }
}

extern "C" void kernel_launch(void* const* d_in, const int* in_sizes, int n_in,
                              void* d_out, int out_size, void* d_ws, size_t ws_size,
                              hipStream_t stream) {
    const float* x = (const float*)d_in[0];
    const float* hist = (const float*)d_in[1];
    const float* ce_w1 = (const float*)d_in[2];
    const float* ce_b1 = (const float*)d_in[3];
    const float* ce_w2 = (const float*)d_in[4];
    const float* ce_b2 = (const float*)d_in[5];
    const float* p_w1 = (const float*)d_in[6];
    const float* p_b1 = (const float*)d_in[7];
    const float* p_w2 = (const float*)d_in[8];
    const float* p_b2 = (const float*)d_in[9];
    const float* wq = (const float*)d_in[10];
    const float* wk = (const float*)d_in[11];

    float* pred_out = (float*)d_out;
    float* A_out = pred_out + (size_t)BTOT * 8;

    k_combine<<<Dm, Dm, 0, stream>>>(wq, wk, p_w2, p_b2);
    k_uwc<<<1, Dm, 0, stream>>>();
    k_frag<<<32, 64, 0, stream>>>();
    k_fused<<<BTOT / 8, 256, 0, stream>>>(x, hist, ce_w1, ce_b1, ce_w2, ce_b2,
                                          p_w1, p_b1, pred_out, A_out);
}

// Round 3
// 168.481 us; speedup vs baseline: 2.2693x; 1.9235x over previous
//
#include <hip/hip_runtime.h>
#include <hip/hip_bf16.h>
#include <stdint.h>

#define Dm 128
#define BTOT (32 * 2048)

typedef short s16x8 __attribute__((ext_vector_type(8)));
typedef float f32x4 __attribute__((ext_vector_type(4)));
typedef float f32x2 __attribute__((ext_vector_type(2)));

__device__ float g_Wq[Dm * Dm];   // Wq_c[g][d] = sum_f wq[g][f] * p_w2[f][d]
__device__ float g_Wk[Dm * Dm];
__device__ float g_bq[Dm], g_bk[Dm];
__device__ __align__(16) unsigned short g_Mfrag[32 * 64 * 8]; // bf16 A-frags of M
__device__ float g_u[Dm], g_w[Dm], g_c[1];
__device__ __align__(16) float g_W1T[40 * Dm];       // [m][d] = ce_w1[d][m]
__device__ __align__(16) float g_W2T4[32 * 64 * 4];  // [(d4*64+o)*4+r] = ce_w2[o][4*d4+r]

__device__ __forceinline__ float fast_sigmoid(float x) { return 1.0f / (1.0f + __expf(-x)); }
__device__ __forceinline__ float fast_tanh(float x) { return 1.0f - 2.0f / (__expf(2.0f * x) + 1.0f); }

__device__ __forceinline__ unsigned short f2bf(float f) {  // RNE f32->bf16
    unsigned u = __float_as_uint(f);
    u += 0x7fffu + ((u >> 16) & 1u);
    return (unsigned short)(u >> 16);
}

// blocks 0..127: combined Wq_c/Wk_c/bq/bk; block 128: transpose ce_w1; block 129: repack ce_w2.
__global__ __launch_bounds__(128) void k_pre1(const float* __restrict__ wq,
                                              const float* __restrict__ wk,
                                              const float* __restrict__ pw2,
                                              const float* __restrict__ pb2,
                                              const float* __restrict__ ce_w1,
                                              const float* __restrict__ ce_w2) {
    const int b = blockIdx.x, t = threadIdx.x;
    if (b < 128) {
        const int g = b, d = t;
        float aq = 0.f, ak = 0.f;
        for (int f = 0; f < Dm; ++f) {
            float pv = pw2[f * Dm + d];
            aq = fmaf(wq[g * Dm + f], pv, aq);
            ak = fmaf(wk[g * Dm + f], pv, ak);
        }
        g_Wq[g * Dm + d] = aq;
        g_Wk[g * Dm + d] = ak;
        if (d == 0) {
            float bq = 0.f, bk = 0.f;
            for (int f = 0; f < Dm; ++f) {
                bq = fmaf(wq[g * Dm + f], pb2[f], bq);
                bk = fmaf(wk[g * Dm + f], pb2[f], bk);
            }
            g_bq[g] = bq;
            g_bk[g] = bk;
        }
    } else if (b == 128) {
#pragma unroll 8
        for (int m = 0; m < 40; ++m) g_W1T[m * Dm + t] = ce_w1[t * 40 + m];
    } else {
        const int o = t & 63, half = t >> 6;
#pragma unroll 4
        for (int dd = 0; dd < 16; ++dd) {
            int d4 = half * 16 + dd;
            f32x4 v = *(const f32x4*)&ce_w2[o * Dm + 4 * d4];
            *(f32x4*)&g_W2T4[(d4 * 64 + o) * 4] = v;
        }
    }
}

// blocks 0..31: M bf16 A-fragments (k-map f(g,j)=4g+(j&3)+16*(j>>2)); block 32: u/w/c.
__global__ __launch_bounds__(128) void k_pre2() {
    const int b = blockIdx.x, tid = threadIdx.x;
    if (b < 32) {
        const int kc = b & 3, rt = b >> 2;
        const int l = tid & 63, jh = tid >> 6;
        const int row = rt * 16 + (l & 15), g = l >> 4;
#pragma unroll
        for (int jj = 0; jj < 4; ++jj) {
            int e = kc * 32 + 4 * g + jj + 16 * jh;
            float acc = 0.f;
            for (int gg = 0; gg < Dm; ++gg)
                acc = fmaf(g_Wq[gg * Dm + row], g_Wk[gg * Dm + e], acc);
            g_Mfrag[(b * 64 + l) * 8 + 4 * jh + jj] = f2bf(acc);
        }
    } else {
        const int d = tid;
        float ua = 0.f, wa = 0.f;
        for (int g = 0; g < Dm; ++g) {
            ua = fmaf(g_Wq[g * Dm + d], g_bk[g], ua);
            wa = fmaf(g_Wk[g * Dm + d], g_bq[g], wa);
        }
        g_u[d] = ua;
        g_w[d] = wa;
        if (d == 0) {
            float c = 0.f;
            for (int g = 0; g < Dm; ++g) c = fmaf(g_bq[g], g_bk[g], c);
            g_c[0] = c;
        }
    }
}

// 256 threads = 4 waves; each wave handles 2 positions (16 RP columns).
__global__ __launch_bounds__(256, 4) void k_fused(const float* __restrict__ x,
                                                  const float* __restrict__ hist,
                                                  const float* __restrict__ ce_b1,
                                                  const float* __restrict__ ce_b2,
                                                  const float* __restrict__ p_w1,
                                                  const float* __restrict__ p_b1,
                                                  float* __restrict__ pred_out,
                                                  float* __restrict__ A_out) {
    __shared__ __align__(16) unsigned short m_lds[32 * 64 * 8];  // 32 KB
    __shared__ __align__(16) float h_s[4][2][128];               // 4 KB
    __shared__ float gate_s[4][2][64];                           // 2 KB

    const int tid = threadIdx.x;
    const int wv = tid >> 6;
    const int l = tid & 63;
    const int g = l >> 4, c16 = l & 15;
    const long bt0 = (long)blockIdx.x * 8 + wv * 2;

    // ---- stage M fragments: global -> LDS, async, drained by the barrier ----
    {
        const char* gsrc = (const char*)g_Mfrag + (size_t)wv * 8192 + (size_t)l * 16;
        char* lbase = (char*)m_lds + wv * 8192;
#pragma unroll
        for (int q = 0; q < 8; ++q) {
            __builtin_amdgcn_global_load_lds(
                (const __attribute__((address_space(1))) unsigned int*)(gsrc + q * 1024),
                (__attribute__((address_space(3))) unsigned int*)(lbase + q * 1024),
                16, 0, 0);
        }
    }

    // ---- rp fragments (bf16, frag layout) + su/sj affine partials ----
    const int p_me = c16 >> 3, i_me = c16 & 7;
    const float xv = x[(bt0 + p_me) * 8 + i_me];
    s16x8 rpf[4];
    float su = 0.f, sj = 0.f;
#pragma unroll
    for (int kc = 0; kc < 4; ++kc) {
#pragma unroll
        for (int jh = 0; jh < 2; ++jh) {
            int d4 = kc * 32 + 4 * g + 16 * jh;
            f32x4 w1v = *(const f32x4*)&p_w1[d4];
            f32x4 b1v = *(const f32x4*)&p_b1[d4];
            f32x4 uv = *(const f32x4*)&g_u[d4];
            f32x4 wvv = *(const f32x4*)&g_w[d4];
#pragma unroll
            for (int jj = 0; jj < 4; ++jj) {
                float val = fmaxf(fmaf(xv, w1v[jj], b1v[jj]), 0.f);
                su = fmaf(uv[jj], val, su);
                sj = fmaf(wvv[jj], val, sj);
                rpf[kc][jh * 4 + jj] = (short)f2bf(val);
            }
        }
    }
    su += __shfl_xor(su, 16); su += __shfl_xor(su, 32);  // full u.rp_{c16}
    sj += __shfl_xor(sj, 16); sj += __shfl_xor(sj, 32);  // full w.rp_{c16}

    // ---- h = relu(ce_w1 @ hist + b1), both positions; coalesced via g_W1T ----
    {
        const int d0 = 2 * l;
        f32x2 b1 = *(const f32x2*)&ce_b1[d0];
        float h00 = b1.x, h01 = b1.y, h10 = b1.x, h11 = b1.y;
        const float* hh0 = hist + bt0 * 40;
        const float* hh1 = hh0 + 40;
#pragma unroll 8
        for (int m = 0; m < 40; ++m) {
            f32x2 w = *(const f32x2*)&g_W1T[m * Dm + d0];
            float v0 = hh0[m], v1 = hh1[m];
            h00 = fmaf(w.x, v0, h00);
            h01 = fmaf(w.y, v0, h01);
            h10 = fmaf(w.x, v1, h10);
            h11 = fmaf(w.y, v1, h11);
        }
        f32x2 e0 = {fmaxf(h00, 0.f), fmaxf(h01, 0.f)};
        f32x2 e1 = {fmaxf(h10, 0.f), fmaxf(h11, 0.f)};
        *(f32x2*)&h_s[wv][0][d0] = e0;
        *(f32x2*)&h_s[wv][1][d0] = e1;
    }

    // ---- gate (lane = output o = i*8+j), coalesced via g_W2T4 ----
    {
        float g0 = ce_b2[l], g1 = g0;
#pragma unroll 8
        for (int d4 = 0; d4 < 32; ++d4) {
            f32x4 w2 = *(const f32x4*)&g_W2T4[(d4 * 64 + l) * 4];
            f32x4 ha = *(const f32x4*)&h_s[wv][0][4 * d4];
            f32x4 hb = *(const f32x4*)&h_s[wv][1][4 * d4];
#pragma unroll
            for (int jj = 0; jj < 4; ++jj) {
                g0 = fmaf(w2[jj], ha[jj], g0);
                g1 = fmaf(w2[jj], hb[jj], g1);
            }
        }
        gate_s[wv][0][l] = fast_sigmoid(g0);
        gate_s[wv][1][l] = fast_sigmoid(g1);
    }

    __syncthreads();  // m_lds staged (vmcnt drained) + visible to all waves

    // ---- Y = M @ RP : 32 MFMAs ----
    f32x4 Yacc[8];
#pragma unroll
    for (int r = 0; r < 8; ++r) Yacc[r] = (f32x4){0.f, 0.f, 0.f, 0.f};
#pragma unroll
    for (int kc = 0; kc < 4; ++kc) {
#pragma unroll
        for (int r = 0; r < 8; ++r) {
            s16x8 af = *(const s16x8*)&m_lds[((r * 4 + kc) * 64 + l) * 8];
            Yacc[r] = __builtin_amdgcn_mfma_f32_16x16x32_bf16(af, rpf[kc], Yacc[r], 0, 0, 0);
        }
    }

    // ---- Y (C-layout) -> bf16 B-frags: direct feed under chosen k-map ----
    s16x8 yf[4];
#pragma unroll
    for (int kc = 0; kc < 4; ++kc) {
#pragma unroll
        for (int jj = 0; jj < 4; ++jj) {
            yf[kc][jj] = (short)f2bf(Yacc[2 * kc][jj]);
            yf[kc][4 + jj] = (short)f2bf(Yacc[2 * kc + 1][jj]);
        }
    }

    // ---- S = RP^T @ Y : 4 MFMAs ----
    f32x4 Sacc = (f32x4){0.f, 0.f, 0.f, 0.f};
#pragma unroll
    for (int kc = 0; kc < 4; ++kc)
        Sacc = __builtin_amdgcn_mfma_f32_16x16x32_bf16(rpf[kc], yf[kc], Sacc, 0, 0, 0);

    // ---- epilogue: scores -> A, pred ----
    const float cc = g_c[0];
    const int np = c16 >> 3, jv = c16 & 7;        // column identity (position, j)
    const bool diag = ((g >> 1) == np);           // row-position == col-position
    float Av[4], pr[4];
#pragma unroll
    for (int q = 0; q < 4; ++q) {
        float su_i = __shfl(su, 4 * g + q);       // u.rp for row i_full = 4g+q
        float sc = (Sacc[q] + su_i + sj + cc) * 0.08838834764831845f;
        float gv = gate_s[wv][np][((g & 1) * 4 + q) * 8 + jv];
        Av[q] = fast_tanh(sc) * gv;
        pr[q] = Av[q] * xv;                       // xv = x[(bt0+np)*8 + jv]
        pr[q] += __shfl_xor(pr[q], 1);
        pr[q] += __shfl_xor(pr[q], 2);
        pr[q] += __shfl_xor(pr[q], 4);
    }
    if (diag) {
        float* Ap = A_out + (bt0 + np) * 64 + jv;
#pragma unroll
        for (int q = 0; q < 4; ++q) Ap[((g & 1) * 4 + q) * 8] = Av[q];
        if (jv == 0) {
            float* Pp = pred_out + (bt0 + np) * 8 + (g & 1) * 4;
#pragma unroll
            for (int q = 0; q < 4; ++q) Pp[q] = pr[q];
        }
    }
}

extern "C" void kernel_launch(void* const* d_in, const int* in_sizes, int n_in,
                              void* d_out, int out_size, void* d_ws, size_t ws_size,
                              hipStream_t stream) {
    const float* x = (const float*)d_in[0];
    const float* hist = (const float*)d_in[1];
    const float* ce_w1 = (const float*)d_in[2];
    const float* ce_b1 = (const float*)d_in[3];
    const float* ce_w2 = (const float*)d_in[4];
    const float* ce_b2 = (const float*)d_in[5];
    const float* p_w1 = (const float*)d_in[6];
    const float* p_b1 = (const float*)d_in[7];
    const float* p_w2 = (const float*)d_in[8];
    const float* p_b2 = (const float*)d_in[9];
    const float* wq = (const float*)d_in[10];
    const float* wk = (const float*)d_in[11];

    float* pred_out = (float*)d_out;
    float* A_out = pred_out + (size_t)BTOT * 8;

    k_pre1<<<130, 128, 0, stream>>>(wq, wk, p_w2, p_b2, ce_w1, ce_w2);
    k_pre2<<<33, 128, 0, stream>>>();
    k_fused<<<BTOT / 8, 256, 0, stream>>>(x, hist, ce_b1, ce_b2,
                                          p_w1, p_b1, pred_out, A_out);
}

// Round 5
// 87.756 us; speedup vs baseline: 4.3569x; 1.9199x over previous
//
#include <hip/hip_runtime.h>
#include <hip/hip_bf16.h>
#include <stdint.h>

#define Dm 128
#define BTOT (32 * 2048)

typedef short s16x8 __attribute__((ext_vector_type(8)));
typedef float f32x4 __attribute__((ext_vector_type(4)));

__device__ float g_Wq[Dm * Dm];   // Wq_c[g][d] = sum_f wq[g][f] * p_w2[f][d]
__device__ float g_Wk[Dm * Dm];
__device__ float g_bq[Dm], g_bk[Dm];
__device__ float g_u[Dm], g_w[Dm], g_c[1];
// frag buffer (shorts): [0,16384) M (32 slots), [16384,24576) W2f (16 slots), [24576,32768) W1f (16 slots)
__device__ __align__(16) unsigned short g_AllFrag[32768];

__device__ __forceinline__ float fast_sigmoid(float x) { return 1.0f / (1.0f + __expf(-x)); }
__device__ __forceinline__ float fast_tanh(float x) { return 1.0f - 2.0f / (__expf(2.0f * x) + 1.0f); }

__device__ __forceinline__ unsigned short f2bf(float f) {  // RNE f32->bf16
    unsigned u = __float_as_uint(f);
    u += 0x7fffu + ((u >> 16) & 1u);
    return (unsigned short)(u >> 16);
}

__device__ __forceinline__ unsigned pk2(float lo, float hi) {  // 2×f32 -> packed 2×bf16
    return (unsigned)f2bf(lo) | ((unsigned)f2bf(hi) << 16);
}

__device__ __forceinline__ s16x8 mk8(unsigned a, unsigned b, unsigned c, unsigned d) {
    union { unsigned u[4]; s16x8 v; } t;
    t.u[0] = a; t.u[1] = b; t.u[2] = c; t.u[3] = d;
    return t.v;
}

// blocks 0..127: combined Wq_c/Wk_c/bq/bk; 128: W1 frags (+bias col k=40); 129: W2 frags.
__global__ __launch_bounds__(128) void k_pre1(const float* __restrict__ wq,
                                              const float* __restrict__ wk,
                                              const float* __restrict__ pw2,
                                              const float* __restrict__ pb2,
                                              const float* __restrict__ ce_w1,
                                              const float* __restrict__ ce_b1,
                                              const float* __restrict__ ce_w2) {
    const int b = blockIdx.x, t = threadIdx.x;
    if (b < 128) {
        const int g = b, d = t;
        float aq = 0.f, ak = 0.f;
        for (int f = 0; f < Dm; ++f) {
            float pv = pw2[f * Dm + d];
            aq = fmaf(wq[g * Dm + f], pv, aq);
            ak = fmaf(wk[g * Dm + f], pv, ak);
        }
        g_Wq[g * Dm + d] = aq;
        g_Wk[g * Dm + d] = ak;
        if (d == 0) {
            float bq = 0.f, bk = 0.f;
            for (int f = 0; f < Dm; ++f) {
                bq = fmaf(wq[g * Dm + f], pb2[f], bq);
                bk = fmaf(wk[g * Dm + f], pb2[f], bk);
            }
            g_bq[g] = bq;
            g_bk[g] = bk;
        }
    } else if (b == 128) {
        // W1f: slot s = rt*2+kc (rt 0..7, kc 0..1); row = 16rt+(l&15); k = kc*32+4g+(j&3)+16*(j>>2)
        for (int s = t; s < 1024; s += 128) {  // s = slot*64 + l
            int l = s & 63, slot = s >> 6;
            int rt = slot >> 1, kc = slot & 1;
            int row = rt * 16 + (l & 15), gg = l >> 4;
#pragma unroll
            for (int j = 0; j < 8; ++j) {
                int k = kc * 32 + 4 * gg + (j & 3) + 16 * (j >> 2);
                float v = (k < 40) ? ce_w1[row * 40 + k] : ((k == 40) ? ce_b1[row] : 0.f);
                g_AllFrag[24576 + s * 8 + j] = f2bf(v);
            }
        }
    } else {
        // W2f: slot = rt2*4+kc (rt2 0..3, kc 0..3); o = 16rt2+(l&15)
        for (int s = t; s < 1024; s += 128) {
            int l = s & 63, slot = s >> 6;
            int rt2 = slot >> 2, kc = slot & 3;
            int o = rt2 * 16 + (l & 15), gg = l >> 4;
#pragma unroll
            for (int j = 0; j < 8; ++j) {
                int k = kc * 32 + 4 * gg + (j & 3) + 16 * (j >> 2);
                g_AllFrag[16384 + s * 8 + j] = f2bf(ce_w2[o * Dm + k]);
            }
        }
    }
}

// blocks 0..31: M bf16 A-frags (slot b = rt*4+kc); block 32: u/w/c.
__global__ __launch_bounds__(128) void k_pre2() {
    const int b = blockIdx.x, tid = threadIdx.x;
    if (b < 32) {
        const int kc = b & 3, rt = b >> 2;
        const int l = tid & 63, jh = tid >> 6;
        const int row = rt * 16 + (l & 15), g = l >> 4;
#pragma unroll
        for (int jj = 0; jj < 4; ++jj) {
            int e = kc * 32 + 4 * g + jj + 16 * jh;
            float acc = 0.f;
            for (int gg = 0; gg < Dm; ++gg)
                acc = fmaf(g_Wq[gg * Dm + row], g_Wk[gg * Dm + e], acc);
            g_AllFrag[(b * 64 + l) * 8 + 4 * jh + jj] = f2bf(acc);
        }
    } else {
        const int d = tid;
        float ua = 0.f, wa = 0.f;
        for (int g = 0; g < Dm; ++g) {
            ua = fmaf(g_Wq[g * Dm + d], g_bk[g], ua);
            wa = fmaf(g_Wk[g * Dm + d], g_bq[g], wa);
        }
        g_u[d] = ua;
        g_w[d] = wa;
        if (d == 0) {
            float c = 0.f;
            for (int g = 0; g < Dm; ++g) c = fmaf(g_bq[g], g_bk[g], c);
            g_c[0] = c;
        }
    }
}

// 512 threads = 8 waves; block handles 16 positions; wave owns 2 for Y/S/epilogue.
__global__ __launch_bounds__(512, 4) void k_fused(const float* __restrict__ x,
                                                  const float* __restrict__ hist,
                                                  const float* __restrict__ ce_b2,
                                                  const float* __restrict__ p_w1,
                                                  const float* __restrict__ p_b1,
                                                  float* __restrict__ pred_out,
                                                  float* __restrict__ A_out) {
    __shared__ __align__(16) unsigned short lds_m[16384];    // M frags, 32 KB
    __shared__ __align__(16) unsigned short lds_hB[2048];    // h in gate-B-frag layout, 4 KB
    __shared__ __align__(16) float lds_hist[640];            // 16 rows x 40
    __shared__ __align__(16) float lds_gate[16][68];         // [block pos][o]

    const int tid = threadIdx.x;
    const int wv = tid >> 6;       // 0..7
    const int l = tid & 63;
    const int g = l >> 4, c16 = l & 15;
    const int blk = blockIdx.x;
    const long bt0 = (long)blk * 16 + wv * 2;

    // ---- A: stage M frags via DMA (proven r3 pattern); hist via plain ld/st ----
    {
        const char* gsrc = (const char*)g_AllFrag + (size_t)wv * 4096 + (size_t)l * 16;
        char* ldst = (char*)lds_m + wv * 4096;
#pragma unroll
        for (int q = 0; q < 4; ++q)
            __builtin_amdgcn_global_load_lds(
                (const __attribute__((address_space(1))) unsigned int*)(gsrc + q * 1024),
                (__attribute__((address_space(3))) unsigned int*)(ldst + q * 1024), 16, 0, 0);
    }
    {
        const float* hsrc = hist + (size_t)blk * 640;
        for (int idx = tid; idx < 640; idx += 512) lds_hist[idx] = hsrc[idx];
    }
    // W1f for this wave's h row-tile (rt = wv): straight to regs
    s16x8 w1fA[2];
#pragma unroll
    for (int kc = 0; kc < 2; ++kc)
        w1fA[kc] = *(const s16x8*)&g_AllFrag[24576 + ((wv * 2 + kc) * 64 + l) * 8];
    // W2f A-frags for gate (waves 0..3, row-tile rt2 = wv): prefetch to regs
    s16x8 w2fA[4];
    if (wv < 4) {
#pragma unroll
        for (int kc = 0; kc < 4; ++kc)
            w2fA[kc] = *(const s16x8*)&g_AllFrag[16384 + ((wv * 4 + kc) * 64 + l) * 8];
    }

    // ---- B: rpf (bf16 frags) + u/w affine partials ----
    const int np = c16 >> 3, i_me = c16 & 7;
    const float xv = x[(bt0 + np) * 8 + i_me];
    s16x8 rpf[4];
    float su = 0.f, sj = 0.f;
#pragma unroll
    for (int kc = 0; kc < 4; ++kc) {
        unsigned wds[4];
#pragma unroll
        for (int jh = 0; jh < 2; ++jh) {
            const int d4 = kc * 32 + 4 * g + 16 * jh;
            f32x4 w1v = *(const f32x4*)&p_w1[d4];
            f32x4 b1v = *(const f32x4*)&p_b1[d4];
            f32x4 uv = *(const f32x4*)&g_u[d4];
            f32x4 wvv = *(const f32x4*)&g_w[d4];
            float v[4];
#pragma unroll
            for (int jj = 0; jj < 4; ++jj) {
                float val = fmaxf(fmaf(xv, w1v[jj], b1v[jj]), 0.f);
                su = fmaf(uv[jj], val, su);
                sj = fmaf(wvv[jj], val, sj);
                v[jj] = val;
            }
            wds[jh * 2 + 0] = pk2(v[0], v[1]);
            wds[jh * 2 + 1] = pk2(v[2], v[3]);
        }
        rpf[kc] = mk8(wds[0], wds[1], wds[2], wds[3]);
    }
    su += __shfl_xor(su, 16); su += __shfl_xor(su, 32);
    sj += __shfl_xor(sj, 16); sj += __shfl_xor(sj, 32);

    __syncthreads();  // bar1: DMA drained, lds_hist visible

    // ---- C: hist B-frags (cols = 16 block positions; bias-1 at k=40) ----
    const float* hl = lds_hist + c16 * 40;
    s16x8 histB[2];
    histB[0] = mk8(pk2(hl[4 * g + 0], hl[4 * g + 1]),
                   pk2(hl[4 * g + 2], hl[4 * g + 3]),
                   pk2(hl[16 + 4 * g + 0], hl[16 + 4 * g + 1]),
                   pk2(hl[16 + 4 * g + 2], hl[16 + 4 * g + 3]));
    {
        float v[4];
#pragma unroll
        for (int jj = 0; jj < 4; ++jj) {
            int k = 32 + 4 * g + jj;           // elements 4..7 (k>=48) are zero
            int kk = (k < 40) ? k : 0;
            float t = hl[kk];
            t = (k < 40) ? t : 0.f;
            v[jj] = (k == 40) ? 1.f : t;       // bias column
        }
        histB[1] = mk8(pk2(v[0], v[1]), pk2(v[2], v[3]), 0u, 0u);
    }

    // ---- D: h MFMA for row-tile rt = wv; publish relu(h) as gate-B-frag slice ----
    f32x4 hC = (f32x4){0.f, 0.f, 0.f, 0.f};
    hC = __builtin_amdgcn_mfma_f32_16x16x32_bf16(w1fA[0], histB[0], hC, 0, 0, 0);
    hC = __builtin_amdgcn_mfma_f32_16x16x32_bf16(w1fA[1], histB[1], hC, 0, 0, 0);
    {
        unsigned* dst = (unsigned*)&lds_hB[((wv >> 1) * 64 + l) * 8 + (wv & 1) * 4];
        dst[0] = pk2(fmaxf(hC[0], 0.f), fmaxf(hC[1], 0.f));
        dst[1] = pk2(fmaxf(hC[2], 0.f), fmaxf(hC[3], 0.f));
    }

    __syncthreads();  // bar2: hB visible

    // ---- E: gate MFMA (waves 0..3: output row-tile rt2 = wv) ----
    if (wv < 4) {
        s16x8 gB[4];
#pragma unroll
        for (int kc = 0; kc < 4; ++kc)
            gB[kc] = *(const s16x8*)&lds_hB[(kc * 64 + l) * 8];
        const int ob = 16 * wv + 4 * g;
        f32x4 gC;
        gC[0] = ce_b2[ob + 0]; gC[1] = ce_b2[ob + 1];
        gC[2] = ce_b2[ob + 2]; gC[3] = ce_b2[ob + 3];
#pragma unroll
        for (int kc = 0; kc < 4; ++kc)
            gC = __builtin_amdgcn_mfma_f32_16x16x32_bf16(w2fA[kc], gB[kc], gC, 0, 0, 0);
        f32x4 sg;
#pragma unroll
        for (int jj = 0; jj < 4; ++jj) sg[jj] = fast_sigmoid(gC[jj]);
        *(f32x4*)&lds_gate[c16][ob] = sg;
    }

    // ---- F: Y = M @ RP (32 MFMAs), yf, S = RP^T @ Y (4 MFMAs) ----
    f32x4 Yacc[8];
#pragma unroll
    for (int r = 0; r < 8; ++r) Yacc[r] = (f32x4){0.f, 0.f, 0.f, 0.f};
#pragma unroll
    for (int kc = 0; kc < 4; ++kc) {
#pragma unroll
        for (int r = 0; r < 8; ++r) {
            s16x8 af = *(const s16x8*)&lds_m[((r * 4 + kc) * 64 + l) * 8];
            Yacc[r] = __builtin_amdgcn_mfma_f32_16x16x32_bf16(af, rpf[kc], Yacc[r], 0, 0, 0);
        }
    }
    s16x8 yf[4];
#pragma unroll
    for (int kc = 0; kc < 4; ++kc)
        yf[kc] = mk8(pk2(Yacc[2 * kc][0], Yacc[2 * kc][1]),
                     pk2(Yacc[2 * kc][2], Yacc[2 * kc][3]),
                     pk2(Yacc[2 * kc + 1][0], Yacc[2 * kc + 1][1]),
                     pk2(Yacc[2 * kc + 1][2], Yacc[2 * kc + 1][3]));
    f32x4 Sacc = (f32x4){0.f, 0.f, 0.f, 0.f};
#pragma unroll
    for (int kc = 0; kc < 4; ++kc)
        Sacc = __builtin_amdgcn_mfma_f32_16x16x32_bf16(rpf[kc], yf[kc], Sacc, 0, 0, 0);

    __syncthreads();  // bar3: lds_gate visible

    // ---- G: epilogue ----
    const float cc = g_c[0];
    const int jv = c16 & 7;
    const bool diag = ((g >> 1) == np);
    const int bp = wv * 2 + np;
    float Av[4], pr[4];
#pragma unroll
    for (int q = 0; q < 4; ++q) {
        float su_i = __shfl(su, 4 * g + q);
        float sc = (Sacc[q] + su_i + sj + cc) * 0.08838834764831845f;
        float gv = lds_gate[bp][(4 * (g & 1) + q) * 8 + jv];
        Av[q] = fast_tanh(sc) * gv;
        pr[q] = Av[q] * xv;
        pr[q] += __shfl_xor(pr[q], 1);
        pr[q] += __shfl_xor(pr[q], 2);
        pr[q] += __shfl_xor(pr[q], 4);
    }
    if (diag) {
        float* Ap = A_out + (bt0 + np) * 64 + jv;
#pragma unroll
        for (int q = 0; q < 4; ++q) Ap[((g & 1) * 4 + q) * 8] = Av[q];
        if (jv == 0) {
            float* Pp = pred_out + (bt0 + np) * 8 + (g & 1) * 4;
#pragma unroll
            for (int q = 0; q < 4; ++q) Pp[q] = pr[q];
        }
    }
}

extern "C" void kernel_launch(void* const* d_in, const int* in_sizes, int n_in,
                              void* d_out, int out_size, void* d_ws, size_t ws_size,
                              hipStream_t stream) {
    const float* x = (const float*)d_in[0];
    const float* hist = (const float*)d_in[1];
    const float* ce_w1 = (const float*)d_in[2];
    const float* ce_b1 = (const float*)d_in[3];
    const float* ce_w2 = (const float*)d_in[4];
    const float* ce_b2 = (const float*)d_in[5];
    const float* p_w1 = (const float*)d_in[6];
    const float* p_b1 = (const float*)d_in[7];
    const float* p_w2 = (const float*)d_in[8];
    const float* p_b2 = (const float*)d_in[9];
    const float* wq = (const float*)d_in[10];
    const float* wk = (const float*)d_in[11];

    float* pred_out = (float*)d_out;
    float* A_out = pred_out + (size_t)BTOT * 8;

    k_pre1<<<130, 128, 0, stream>>>(wq, wk, p_w2, p_b2, ce_w1, ce_b1, ce_w2);
    k_pre2<<<33, 128, 0, stream>>>();
    k_fused<<<BTOT / 16, 512, 0, stream>>>(x, hist, ce_b2, p_w1, p_b1, pred_out, A_out);
}

// Round 6
// 84.754 us; speedup vs baseline: 4.5112x; 1.0354x over previous
//
#include <hip/hip_runtime.h>
#include <hip/hip_bf16.h>
#include <stdint.h>

#define Dm 128
#define BTOT (32 * 2048)

typedef short s16x8 __attribute__((ext_vector_type(8)));
typedef float f32x4 __attribute__((ext_vector_type(4)));

__device__ float g_Wq[Dm * Dm];   // Wq_c[g][d] = sum_f wq[g][f] * p_w2[f][d]
__device__ float g_Wk[Dm * Dm];
__device__ float g_bq[Dm], g_bk[Dm];
__device__ float g_u[Dm], g_w[Dm], g_c[1];
// frag buffer (shorts): [0,16384) M (32 slots), [16384,24576) W2f (16 slots), [24576,32768) W1f (16 slots)
__device__ __align__(16) unsigned short g_AllFrag[32768];

__device__ __forceinline__ float fast_sigmoid(float x) { return 1.0f / (1.0f + __expf(-x)); }
__device__ __forceinline__ float fast_tanh(float x) { return 1.0f - 2.0f / (__expf(2.0f * x) + 1.0f); }

__device__ __forceinline__ unsigned short f2bf(float f) {  // RNE f32->bf16 (precompute only)
    unsigned u = __float_as_uint(f);
    u += 0x7fffu + ((u >> 16) & 1u);
    return (unsigned short)(u >> 16);
}

__device__ __forceinline__ unsigned pk2(float lo, float hi) {  // 2×f32 -> packed 2×bf16 (RNE fptrunc)
    unsigned short ua = __builtin_bit_cast(unsigned short, (__bf16)lo);
    unsigned short ub = __builtin_bit_cast(unsigned short, (__bf16)hi);
    return (unsigned)ua | ((unsigned)ub << 16);
}

__device__ __forceinline__ s16x8 mk8(unsigned a, unsigned b, unsigned c, unsigned d) {
    union { unsigned u[4]; s16x8 v; } t;
    t.u[0] = a; t.u[1] = b; t.u[2] = c; t.u[3] = d;
    return t.v;
}

// blocks 0..127: combined Wq_c/Wk_c/bq/bk; 128: W1 frags (+bias col k=40); 129: W2 frags.
__global__ __launch_bounds__(128) void k_pre1(const float* __restrict__ wq,
                                              const float* __restrict__ wk,
                                              const float* __restrict__ pw2,
                                              const float* __restrict__ pb2,
                                              const float* __restrict__ ce_w1,
                                              const float* __restrict__ ce_b1,
                                              const float* __restrict__ ce_w2) {
    const int b = blockIdx.x, t = threadIdx.x;
    if (b < 128) {
        const int g = b, d = t;
        float aq = 0.f, ak = 0.f;
        for (int f = 0; f < Dm; ++f) {
            float pv = pw2[f * Dm + d];
            aq = fmaf(wq[g * Dm + f], pv, aq);
            ak = fmaf(wk[g * Dm + f], pv, ak);
        }
        g_Wq[g * Dm + d] = aq;
        g_Wk[g * Dm + d] = ak;
        if (d == 0) {
            float bq = 0.f, bk = 0.f;
            for (int f = 0; f < Dm; ++f) {
                bq = fmaf(wq[g * Dm + f], pb2[f], bq);
                bk = fmaf(wk[g * Dm + f], pb2[f], bk);
            }
            g_bq[g] = bq;
            g_bk[g] = bk;
        }
    } else if (b == 128) {
        // W1f: slot s = rt*2+kc (rt 0..7, kc 0..1); row = 16rt+(l&15); k = kc*32+4g+(j&3)+16*(j>>2)
        for (int s = t; s < 1024; s += 128) {  // s = slot*64 + l
            int l = s & 63, slot = s >> 6;
            int rt = slot >> 1, kc = slot & 1;
            int row = rt * 16 + (l & 15), gg = l >> 4;
#pragma unroll
            for (int j = 0; j < 8; ++j) {
                int k = kc * 32 + 4 * gg + (j & 3) + 16 * (j >> 2);
                float v = (k < 40) ? ce_w1[row * 40 + k] : ((k == 40) ? ce_b1[row] : 0.f);
                g_AllFrag[24576 + s * 8 + j] = f2bf(v);
            }
        }
    } else {
        // W2f: slot = rt2*4+kc (rt2 0..3, kc 0..3); o = 16rt2+(l&15)
        for (int s = t; s < 1024; s += 128) {
            int l = s & 63, slot = s >> 6;
            int rt2 = slot >> 2, kc = slot & 3;
            int o = rt2 * 16 + (l & 15), gg = l >> 4;
#pragma unroll
            for (int j = 0; j < 8; ++j) {
                int k = kc * 32 + 4 * gg + (j & 3) + 16 * (j >> 2);
                g_AllFrag[16384 + s * 8 + j] = f2bf(ce_w2[o * Dm + k]);
            }
        }
    }
}

// blocks 0..31: M bf16 A-frags (slot b = rt*4+kc); block 32: u/w/c.
__global__ __launch_bounds__(128) void k_pre2() {
    const int b = blockIdx.x, tid = threadIdx.x;
    if (b < 32) {
        const int kc = b & 3, rt = b >> 2;
        const int l = tid & 63, jh = tid >> 6;
        const int row = rt * 16 + (l & 15), g = l >> 4;
#pragma unroll
        for (int jj = 0; jj < 4; ++jj) {
            int e = kc * 32 + 4 * g + jj + 16 * jh;
            float acc = 0.f;
            for (int gg = 0; gg < Dm; ++gg)
                acc = fmaf(g_Wq[gg * Dm + row], g_Wk[gg * Dm + e], acc);
            g_AllFrag[(b * 64 + l) * 8 + 4 * jh + jj] = f2bf(acc);
        }
    } else {
        const int d = tid;
        float ua = 0.f, wa = 0.f;
        for (int g = 0; g < Dm; ++g) {
            ua = fmaf(g_Wq[g * Dm + d], g_bk[g], ua);
            wa = fmaf(g_Wk[g * Dm + d], g_bq[g], wa);
        }
        g_u[d] = ua;
        g_w[d] = wa;
        if (d == 0) {
            float c = 0.f;
            for (int g = 0; g < Dm; ++g) c = fmaf(g_bq[g], g_bk[g], c);
            g_c[0] = c;
        }
    }
}

// 512 threads = 8 waves; block handles 16 positions; wave owns 2 for Y/S/epilogue.
__global__ __launch_bounds__(512, 4) void k_fused(const float* __restrict__ x,
                                                  const float* __restrict__ hist,
                                                  const float* __restrict__ ce_b2,
                                                  const float* __restrict__ p_w1,
                                                  const float* __restrict__ p_b1,
                                                  float* __restrict__ pred_out,
                                                  float* __restrict__ A_out) {
    __shared__ __align__(16) unsigned short lds_m[16384];    // M frags, 32 KB
    __shared__ __align__(16) unsigned short lds_hB[2048];    // h in gate-B-frag layout, 4 KB
    __shared__ __align__(16) float lds_hist[16 * 41];        // padded stride 41 (bank stride 9)
    __shared__ __align__(16) float lds_gate[16][68];         // [block pos][o]

    const int tid = threadIdx.x;
    const int wv = tid >> 6;       // 0..7
    const int l = tid & 63;
    const int g = l >> 4, c16 = l & 15;
    const int blk = blockIdx.x;
    const long bt0 = (long)blk * 16 + wv * 2;

    // ---- A: stage M frags via DMA; hist via plain ld/st (padded rows) ----
    {
        const char* gsrc = (const char*)g_AllFrag + (size_t)wv * 4096 + (size_t)l * 16;
        char* ldst = (char*)lds_m + wv * 4096;
#pragma unroll
        for (int q = 0; q < 4; ++q)
            __builtin_amdgcn_global_load_lds(
                (const __attribute__((address_space(1))) unsigned int*)(gsrc + q * 1024),
                (__attribute__((address_space(3))) unsigned int*)(ldst + q * 1024), 16, 0, 0);
    }
    {
        const float* hsrc = hist + (size_t)blk * 640;
        for (int idx = tid; idx < 640; idx += 512)
            lds_hist[(idx / 40) * 41 + (idx % 40)] = hsrc[idx];
    }
    // W1f for this wave's h row-tile (rt = wv): straight to regs
    s16x8 w1fA[2];
#pragma unroll
    for (int kc = 0; kc < 2; ++kc)
        w1fA[kc] = *(const s16x8*)&g_AllFrag[24576 + ((wv * 2 + kc) * 64 + l) * 8];
    // W2f A-frags for gate (waves 0..3, row-tile rt2 = wv): prefetch to regs
    s16x8 w2fA[4];
    if (wv < 4) {
#pragma unroll
        for (int kc = 0; kc < 4; ++kc)
            w2fA[kc] = *(const s16x8*)&g_AllFrag[16384 + ((wv * 4 + kc) * 64 + l) * 8];
    }

    // ---- B: rpf (bf16 frags) + w-affine partial (u folded into Yacc init) ----
    const int np = c16 >> 3, i_me = c16 & 7;
    const float xv = x[(bt0 + np) * 8 + i_me];
    s16x8 rpf[4];
    float sj = 0.f;
#pragma unroll
    for (int kc = 0; kc < 4; ++kc) {
        unsigned wds[4];
#pragma unroll
        for (int jh = 0; jh < 2; ++jh) {
            const int d4 = kc * 32 + 4 * g + 16 * jh;
            f32x4 w1v = *(const f32x4*)&p_w1[d4];
            f32x4 b1v = *(const f32x4*)&p_b1[d4];
            f32x4 wvv = *(const f32x4*)&g_w[d4];
            float v[4];
#pragma unroll
            for (int jj = 0; jj < 4; ++jj) {
                float val = fmaxf(fmaf(xv, w1v[jj], b1v[jj]), 0.f);
                sj = fmaf(wvv[jj], val, sj);
                v[jj] = val;
            }
            wds[jh * 2 + 0] = pk2(v[0], v[1]);
            wds[jh * 2 + 1] = pk2(v[2], v[3]);
        }
        rpf[kc] = mk8(wds[0], wds[1], wds[2], wds[3]);
    }
    sj += __shfl_xor(sj, 16); sj += __shfl_xor(sj, 32);

    __syncthreads();  // bar1: DMA drained, lds_hist visible

    // ---- C: hist B-frags (cols = 16 block positions; bias-1 at k=40) ----
    const float* hl = lds_hist + c16 * 41;
    s16x8 histB[2];
    histB[0] = mk8(pk2(hl[4 * g + 0], hl[4 * g + 1]),
                   pk2(hl[4 * g + 2], hl[4 * g + 3]),
                   pk2(hl[16 + 4 * g + 0], hl[16 + 4 * g + 1]),
                   pk2(hl[16 + 4 * g + 2], hl[16 + 4 * g + 3]));
    {
        float v[4];
#pragma unroll
        for (int jj = 0; jj < 4; ++jj) {
            int k = 32 + 4 * g + jj;           // elements 4..7 (k>=48) are zero
            int kk = (k < 40) ? k : 0;
            float t = hl[kk];
            t = (k < 40) ? t : 0.f;
            v[jj] = (k == 40) ? 1.f : t;       // bias column
        }
        histB[1] = mk8(pk2(v[0], v[1]), pk2(v[2], v[3]), 0u, 0u);
    }

    // ---- D: h MFMA for row-tile rt = wv; publish relu(h) as gate-B-frag slice ----
    f32x4 hC = (f32x4){0.f, 0.f, 0.f, 0.f};
    hC = __builtin_amdgcn_mfma_f32_16x16x32_bf16(w1fA[0], histB[0], hC, 0, 0, 0);
    hC = __builtin_amdgcn_mfma_f32_16x16x32_bf16(w1fA[1], histB[1], hC, 0, 0, 0);
    {
        unsigned* dst = (unsigned*)&lds_hB[((wv >> 1) * 64 + l) * 8 + (wv & 1) * 4];
        dst[0] = pk2(fmaxf(hC[0], 0.f), fmaxf(hC[1], 0.f));
        dst[1] = pk2(fmaxf(hC[2], 0.f), fmaxf(hC[3], 0.f));
    }

    __syncthreads();  // bar2: hB visible

    // ---- E: gate MFMA (waves 0..3: output row-tile rt2 = wv) ----
    if (wv < 4) {
        s16x8 gB[4];
#pragma unroll
        for (int kc = 0; kc < 4; ++kc)
            gB[kc] = *(const s16x8*)&lds_hB[(kc * 64 + l) * 8];
        const int ob = 16 * wv + 4 * g;
        f32x4 gC;
        gC[0] = ce_b2[ob + 0]; gC[1] = ce_b2[ob + 1];
        gC[2] = ce_b2[ob + 2]; gC[3] = ce_b2[ob + 3];
#pragma unroll
        for (int kc = 0; kc < 4; ++kc)
            gC = __builtin_amdgcn_mfma_f32_16x16x32_bf16(w2fA[kc], gB[kc], gC, 0, 0, 0);
        f32x4 sg;
#pragma unroll
        for (int jj = 0; jj < 4; ++jj) sg[jj] = fast_sigmoid(gC[jj]);
        *(f32x4*)&lds_gate[c16][ob] = sg;
    }

    // ---- F: Y = M @ RP + u (32 MFMAs; u as C-init), yf, S = RP^T @ Y' (4 MFMAs) ----
    f32x4 Yacc[8];
#pragma unroll
    for (int r = 0; r < 8; ++r) Yacc[r] = *(const f32x4*)&g_u[16 * r + 4 * g];
#pragma unroll
    for (int kc = 0; kc < 4; ++kc) {
#pragma unroll
        for (int r = 0; r < 8; ++r) {
            s16x8 af = *(const s16x8*)&lds_m[((r * 4 + kc) * 64 + l) * 8];
            Yacc[r] = __builtin_amdgcn_mfma_f32_16x16x32_bf16(af, rpf[kc], Yacc[r], 0, 0, 0);
        }
    }
    s16x8 yf[4];
#pragma unroll
    for (int kc = 0; kc < 4; ++kc)
        yf[kc] = mk8(pk2(Yacc[2 * kc][0], Yacc[2 * kc][1]),
                     pk2(Yacc[2 * kc][2], Yacc[2 * kc][3]),
                     pk2(Yacc[2 * kc + 1][0], Yacc[2 * kc + 1][1]),
                     pk2(Yacc[2 * kc + 1][2], Yacc[2 * kc + 1][3]));
    f32x4 Sacc = (f32x4){0.f, 0.f, 0.f, 0.f};
#pragma unroll
    for (int kc = 0; kc < 4; ++kc)
        Sacc = __builtin_amdgcn_mfma_f32_16x16x32_bf16(rpf[kc], yf[kc], Sacc, 0, 0, 0);

    __syncthreads();  // bar3: lds_gate visible

    // ---- G: epilogue ----
    const float cc = g_c[0];
    const int jv = c16 & 7;
    const bool diag = ((g >> 1) == np);
    const int bp = wv * 2 + np;
    float Av[4], pr[4];
#pragma unroll
    for (int q = 0; q < 4; ++q) {
        float sc = (Sacc[q] + sj + cc) * 0.08838834764831845f;
        float gv = lds_gate[bp][(4 * (g & 1) + q) * 8 + jv];
        Av[q] = fast_tanh(sc) * gv;
        pr[q] = Av[q] * xv;
        pr[q] += __shfl_xor(pr[q], 1);
        pr[q] += __shfl_xor(pr[q], 2);
        pr[q] += __shfl_xor(pr[q], 4);
    }
    if (diag) {
        float* Ap = A_out + (bt0 + np) * 64 + jv;
#pragma unroll
        for (int q = 0; q < 4; ++q) Ap[((g & 1) * 4 + q) * 8] = Av[q];
        if (jv == 0) {
            float* Pp = pred_out + (bt0 + np) * 8 + (g & 1) * 4;
#pragma unroll
            for (int q = 0; q < 4; ++q) Pp[q] = pr[q];
        }
    }
}

extern "C" void kernel_launch(void* const* d_in, const int* in_sizes, int n_in,
                              void* d_out, int out_size, void* d_ws, size_t ws_size,
                              hipStream_t stream) {
    const float* x = (const float*)d_in[0];
    const float* hist = (const float*)d_in[1];
    const float* ce_w1 = (const float*)d_in[2];
    const float* ce_b1 = (const float*)d_in[3];
    const float* ce_w2 = (const float*)d_in[4];
    const float* ce_b2 = (const float*)d_in[5];
    const float* p_w1 = (const float*)d_in[6];
    const float* p_b1 = (const float*)d_in[7];
    const float* p_w2 = (const float*)d_in[8];
    const float* p_b2 = (const float*)d_in[9];
    const float* wq = (const float*)d_in[10];
    const float* wk = (const float*)d_in[11];

    float* pred_out = (float*)d_out;
    float* A_out = pred_out + (size_t)BTOT * 8;

    k_pre1<<<130, 128, 0, stream>>>(wq, wk, p_w2, p_b2, ce_w1, ce_b1, ce_w2);
    k_pre2<<<33, 128, 0, stream>>>();
    k_fused<<<BTOT / 16, 512, 0, stream>>>(x, hist, ce_b2, p_w1, p_b1, pred_out, A_out);
}